// Round 10
// baseline (270.781 us; speedup 1.0000x reference)
//
#include <hip/hip_runtime.h>
#include <stdint.h>

#define NVOX 40000
#define CCH  128
#define K2   9
#define NH   5
#define TILES 313   // ceil(40000/128)

typedef __attribute__((ext_vector_type(8))) short bf16x8;
typedef __attribute__((ext_vector_type(4))) float f32x4;

__device__ __forceinline__ unsigned short f2b(float f) {
  union { float f; unsigned int u; } v; v.f = f;
  return (unsigned short)((v.u + 0x7fffu + ((v.u >> 16) & 1u)) >> 16);
}
__device__ __forceinline__ float b2f(unsigned short u) {
  union { unsigned int u; float f; } v; v.u = ((unsigned int)u) << 16;
  return v.f;
}
__device__ __forceinline__ void g2l16(const void* g, void* l) {
  __builtin_amdgcn_global_load_lds(
      (const __attribute__((address_space(1))) unsigned int*)g,
      (__attribute__((address_space(3))) unsigned int*)l, 16, 0, 0);
}
// XOR-swizzled LDS address (shorts) for logical (row, short-col), 128-wide
__device__ __forceinline__ int swz(int row, int col) {
  return row * 128 + ((((col >> 3) ^ (row & 15)) << 3) | (col & 7));
}

// ---- fused prep: feats fp32->bf16 | W1 cvt+transpose | sums zero ----
__global__ void prep(const float4* __restrict__ feats, ushort4* __restrict__ fb,
                     const float* __restrict__ w1, unsigned short* __restrict__ w1t,
                     float* __restrict__ sums) {
  __shared__ unsigned short t[64 * 34];
  int b = blockIdx.x;
  if (b < 5000) {
    int i = b * 256 + threadIdx.x;
    if (i < NVOX * CCH / 4) {
      float4 v = feats[i];
      ushort4 r;
      r.x = f2b(v.x); r.y = f2b(v.y); r.z = f2b(v.z); r.w = f2b(v.w);
      fb[i] = r;
    }
    return;
  }
  if (b == 5360) {  // zero BN partial sums (ws is poisoned each call)
    for (int i = threadIdx.x; i < 2 * NH * CCH; i += 256) sums[i] = 0.f;
    return;
  }
  int bb = b - 5000;           // 0..359
  int tile = bb >> 3;          // h*9+k, 0..44
  int q = (bb >> 1) & 3;       // c-quarter (32 c each)
  int dh = bb & 1;             // d-half (64 d each)
  const float* src = w1 + (size_t)tile * 16384 + q * 32 * 128 + dh * 64;
  for (int e = threadIdx.x; e < 2048; e += 256) {
    int c = e >> 6, dd = e & 63;
    t[dd * 34 + c] = f2b(src[c * 128 + dd]);
  }
  __syncthreads();
  unsigned short* dst = w1t + (size_t)tile * 16384 + q * 32;
  for (int e = threadIdx.x; e < 2048; e += 256) {
    int d = e >> 5, c = e & 31;
    dst[(dh * 64 + d) * 128 + c] = t[d * 34 + c];
  }
}

// stage one HALF B tile (128 d-rows x 64 c-cols = 16 KB) into LDS with 8
// waves: 2 g2l16 per wave, each covers 8 rows x 64 cols (1 KB). Swizzle:
// logical chunk g of row r stored at slot g ^ (r&7).
__device__ __forceinline__ void stageBhalf8(unsigned short* dst, const unsigned short* wp_tap,
                                            int half, int wave, int lane) {
  int lrow = lane >> 3;   // 0..7
  int lch  = lane & 7;    // chunk slot
#pragma unroll
  for (int i = 0; i < 2; ++i) {
    int blk = wave * 2 + i;          // 0..15, 8 rows each
    g2l16(wp_tap + (blk * 8 + lrow) * 128 + half * 64 + ((lch ^ lrow) << 3),
          &dst[blk * 512]);
  }
}

// ---- gather-GEMM v10: 512 thr / 8 waves; wave owns 32 rows x 64 cols
// (wr=wave>>1, wc=wave&1) -> B-reads per MFMA = 0.5. B in a 3-ring of 16 KB
// half-tiles staged 2 phases ahead; A frags in registers prefetched one
// half-tap ahead. Phase-end: s_waitcnt vmcnt(2) (drains S(p+1)+A, leaves
// S(p+2) in flight) + raw s_barrier -> loads cross the barrier. ----
__global__ void __launch_bounds__(512, 4) conv_gemm(
    const unsigned short* __restrict__ fb,   // feats bf16 [N][128]
    const int* __restrict__ nbr,             // [N][9]
    const unsigned short* __restrict__ w1t,  // [H][9][d=128][c=128] bf16
    unsigned short* __restrict__ yb,         // [H][N][128] bf16
    float* __restrict__ sums)                // [2][H][128]
{
  __shared__ __align__(16) unsigned short Bsb[3][64 * 128];   // 48 KB
  __shared__ int idxs[128 * K2];                              // 4.6 KB

  const int bid = blockIdx.x;
  const int s = bid / 40;
  const int r = bid % 40;
  const int h = r >> 3;        // 0..4
  const int x = r & 7;         // xcd lane
  const int tile = s * 8 + x;
  if (tile >= TILES) return;
  const int n0 = tile * 128;

  const int tid = threadIdx.x;
  const int wave = tid >> 6;   // 0..7
  const int lane = tid & 63;
  const int m = lane & 15;
  const int quad = lane >> 4;  // 0..3
  const int wr = wave >> 1;    // row group (32 rows)
  const int wc = wave & 1;     // col half (64 cols)

  const unsigned short* wh = w1t + ((size_t)h * K2 << 14);

  // idxs first (own barrier) so its loads don't pollute the vmcnt queue
  for (int i = tid; i < 128 * K2; i += 512) {
    int rr = i / K2;
    int gn = n0 + rr; if (gn > NVOX - 1) gn = NVOX - 1;
    idxs[i] = nbr[gn * K2 + (i - rr * K2)];
  }
  __syncthreads();

  // A parity regs: [par][rowfrag][kcL]; rows wr*32+m and wr*32+16+m
  bf16x8 A[2][2][2];

  // prologue: issue S0(2), A(phase0)(4), S1(2) -> vmcnt(2) leaves S1 in flight
  stageBhalf8(Bsb[0], wh, 0, wave, lane);
  {
    int i0 = idxs[(wr * 32 + m) * K2 + 0];
    int i1 = idxs[(wr * 32 + 16 + m) * K2 + 0];
    const unsigned short* p0 = fb + (size_t)i0 * CCH + quad * 8;
    const unsigned short* p1 = fb + (size_t)i1 * CCH + quad * 8;
    A[0][0][0] = *(const bf16x8*)(p0);
    A[0][0][1] = *(const bf16x8*)(p0 + 32);
    A[0][1][0] = *(const bf16x8*)(p1);
    A[0][1][1] = *(const bf16x8*)(p1 + 32);
  }
  stageBhalf8(Bsb[1], wh, 1, wave, lane);
  asm volatile("s_waitcnt vmcnt(2)" ::: "memory");
  __builtin_amdgcn_s_barrier();

  f32x4 acc[2][4] = {};

  // 18 phases: phase p = tap p>>1, kc-pair p&1, buffer p%3
#pragma unroll
  for (int p = 0; p < 18; ++p) {
    const int par = p & 1;

    // 1. A prefetch for phase p+1 (oldest in this phase's issue group after S(p+1))
    if (p < 17) {
      int tn = (p + 1) >> 1, kp = (p + 1) & 1;
      int i0 = idxs[(wr * 32 + m) * K2 + tn];
      int i1 = idxs[(wr * 32 + 16 + m) * K2 + tn];
      const unsigned short* p0 = fb + (size_t)i0 * CCH + kp * 64 + quad * 8;
      const unsigned short* p1 = fb + (size_t)i1 * CCH + kp * 64 + quad * 8;
      A[par ^ 1][0][0] = *(const bf16x8*)(p0);
      A[par ^ 1][0][1] = *(const bf16x8*)(p0 + 32);
      A[par ^ 1][1][0] = *(const bf16x8*)(p1);
      A[par ^ 1][1][1] = *(const bf16x8*)(p1 + 32);
    }
    // 2. stage S(p+2) into ring buffer (freed at end of phase p-1)
    if (p < 16)
      stageBhalf8(Bsb[(p + 2) % 3], wh + ((size_t)((p + 2) >> 1) << 14),
                  (p + 2) & 1, wave, lane);

    // 3. compute: kcL 0,1 from Bsb[p%3] (this wave's 64-col half)
    const unsigned short* Bcur = Bsb[p % 3];
#pragma unroll
    for (int kcL = 0; kcL < 2; ++kcL) {
      bf16x8 bfr[4];
#pragma unroll
      for (int nj = 0; nj < 4; ++nj) {
        int row = wc * 64 + nj * 16 + m;
        bfr[nj] = *(const bf16x8*)&Bcur[row * 64 + (((kcL * 4 + quad) ^ (m & 7)) << 3)];
      }
#pragma unroll
      for (int nj = 0; nj < 4; ++nj) {
        acc[0][nj] = __builtin_amdgcn_mfma_f32_16x16x32_bf16(A[par][0][kcL], bfr[nj], acc[0][nj], 0, 0, 0);
        acc[1][nj] = __builtin_amdgcn_mfma_f32_16x16x32_bf16(A[par][1][kcL], bfr[nj], acc[1][nj], 0, 0, 0);
      }
    }

    // 4. wait (leave S(p+2) in flight) + barrier
    if (p < 16) {
      asm volatile("s_waitcnt vmcnt(2)" ::: "memory");
      __builtin_amdgcn_s_barrier();
    } else if (p == 16) {
      asm volatile("s_waitcnt vmcnt(0)" ::: "memory");
      __builtin_amdgcn_s_barrier();
    }
    // p == 17: no stage/prefetch issued; epilogue barrier follows
  }

  // ---- epilogue ----
  const bool full = (n0 + 128 <= NVOX);
  // epi (32 KB) overlays Bsb[0..1] (safe: all waves past p=16 barrier);
  // pb overlays Bsb[2] (needs barrier: some waves may still read S17=Bsb[2])
  unsigned short* epi = &Bsb[0][0];

  // C/D layout: row (voxel) = quad*4+reg, col (d) = m
#pragma unroll
  for (int mi = 0; mi < 2; ++mi)
#pragma unroll
    for (int nj = 0; nj < 4; ++nj)
#pragma unroll
      for (int rr = 0; rr < 4; ++rr) {
        int row = wr * 32 + mi * 16 + quad * 4 + rr;
        int col = wc * 64 + nj * 16 + m;
        epi[swz(row, col)] = f2b(acc[mi][nj][rr]);
      }

  // BN partials from acc; quad-reduce via shfl (lane bits 4,5)
  float psm[4], pq[4];
#pragma unroll
  for (int nj = 0; nj < 4; ++nj) {
    float sm = 0.f, q = 0.f;
#pragma unroll
    for (int mi = 0; mi < 2; ++mi)
#pragma unroll
      for (int rr = 0; rr < 4; ++rr) {
        float v = acc[mi][nj][rr];
        if (!full && n0 + wr * 32 + mi * 16 + quad * 4 + rr >= NVOX) v = 0.f;
        sm += v; q += v * v;
      }
    sm += __shfl_xor(sm, 16); q += __shfl_xor(q, 16);
    sm += __shfl_xor(sm, 32); q += __shfl_xor(q, 32);
    psm[nj] = sm; pq[nj] = q;
  }
  __syncthreads();   // epi written everywhere; Bsb[2] free for pb

  float2* pb = (float2*)&Bsb[2][0];   // [128 cols][5 pad] float2 = 5 KB
  if (quad == 0)
#pragma unroll
    for (int nj = 0; nj < 4; ++nj)
      pb[(wc * 64 + nj * 16 + m) * 5 + wr] = make_float2(psm[nj], pq[nj]);

  // coalesced y store (un-swizzle on read)
  for (int i = tid; i < 2048; i += 512) {
    int row = i >> 4;
    int c = i & 15;
    if (n0 + row < NVOX)
      *(bf16x8*)(yb + ((size_t)h * NVOX + n0 + row) * CCH + c * 8) =
          *(const bf16x8*)&epi[row * 128 + ((c ^ (row & 15)) << 3)];
  }
  __syncthreads();

  if (tid < 128) {
    float sm = 0.f, q = 0.f;
#pragma unroll
    for (int c = 0; c < 4; ++c) {
      float2 pv = pb[tid * 5 + c];
      sm += pv.x; q += pv.y;
    }
    atomicAdd(&sums[h * CCH + tid], sm);
    atomicAdd(&sums[NH * CCH + h * CCH + tid], q);
  }
}

// ---- BN + ReLU + 1x1 head, one (64-voxel tile, head) per block ----
__global__ void __launch_bounds__(256) head_fuse(
    const unsigned short* __restrict__ yb, const float* __restrict__ sums,
    const float* __restrict__ gamma, const float* __restrict__ beta,
    const float* __restrict__ w_hm, const float* __restrict__ b_hm,
    const float* __restrict__ w_ce, const float* __restrict__ b_ce,
    const float* __restrict__ w_cz, const float* __restrict__ b_cz,
    const float* __restrict__ w_dm, const float* __restrict__ b_dm,
    const float* __restrict__ w_rt, const float* __restrict__ b_rt,
    float* __restrict__ out)
{
  __shared__ unsigned short t[64 * 128];   // 16 KB, swizzled
  __shared__ float pbuf[4][64][3];         // 3 KB
  __shared__ float scl[CCH], shf[CCH];     // 1 KB

  const int tid = threadIdx.x;
  const int h  = blockIdx.x % NH;
  const int v0 = (blockIdx.x / NH) * 64;   // 625 v-tiles cover 40000
  const int vx = tid & 63;
  const int qd = tid >> 6;                 // wave-uniform d-quarter

  const float* wp; const float* bp; int oc, off;
  switch (h) {
    case 0: wp = w_hm; bp = b_hm; oc = 3; off = 0; break;
    case 1: wp = w_ce; bp = b_ce; oc = 2; off = 3; break;
    case 2: wp = w_cz; bp = b_cz; oc = 1; off = 5; break;
    case 3: wp = w_dm; bp = b_dm; oc = 3; off = 6; break;
    default: wp = w_rt; bp = b_rt; oc = 2; off = 9; break;
  }

  // BN finalize for this head's 128 channels
  if (tid < CCH) {
    int i = h * CCH + tid;
    float mean = sums[i] * (1.f / NVOX);
    float var = sums[NH * CCH + i] * (1.f / NVOX) - mean * mean;
    float rstd = rsqrtf(var + 1e-5f);
    float sc = rstd * gamma[i];
    scl[tid] = sc;
    shf[tid] = beta[i] - mean * sc;
  }
  // stage 64 rows coalesced
#pragma unroll
  for (int i = 0; i < 4; ++i) {
    int idx = i * 256 + tid;
    int row = idx >> 4, c = idx & 15;
    *(bf16x8*)&t[row * 128 + ((c ^ (row & 15)) << 3)] =
        *(const bf16x8*)(yb + ((size_t)h * NVOX + v0 + row) * CCH + c * 8);
  }
  __syncthreads();

  float p0 = 0.f, p1 = 0.f, p2 = 0.f;
#pragma unroll
  for (int qq = 0; qq < 4; ++qq) {
    int q8 = qd * 4 + qq;
    bf16x8 pk = *(const bf16x8*)&t[vx * 128 + ((q8 ^ (vx & 15)) << 3)];
#pragma unroll
    for (int e = 0; e < 8; ++e) {
      int d = q8 * 8 + e;
      float z = fmaf(b2f((unsigned short)pk[e]), scl[d], shf[d]);
      z = fmaxf(z, 0.f);
      const float* wr = wp + d * oc;
      p0 = fmaf(z, wr[0], p0);
      if (oc > 1) p1 = fmaf(z, wr[1], p1);
      if (oc > 2) p2 = fmaf(z, wr[2], p2);
    }
  }
  pbuf[qd][vx][0] = p0;
  if (oc > 1) pbuf[qd][vx][1] = p1;
  if (oc > 2) pbuf[qd][vx][2] = p2;
  __syncthreads();

  if (tid < 64) {
    float* op = out + (size_t)(v0 + tid) * 11 + off;
#pragma unroll
    for (int j = 0; j < 3; ++j)
      if (j < oc)
        op[j] = bp[j] + pbuf[0][tid][j] + pbuf[1][tid][j] + pbuf[2][tid][j] + pbuf[3][tid][j];
  }
}

extern "C" void kernel_launch(void* const* d_in, const int* in_sizes, int n_in,
                              void* d_out, int out_size, void* d_ws, size_t ws_size,
                              hipStream_t stream) {
  const float* feats = (const float*)d_in[0];
  const int*   nbr   = (const int*)d_in[1];
  const float* W1    = (const float*)d_in[2];
  const float* gamma = (const float*)d_in[3];
  const float* beta  = (const float*)d_in[4];
  const float* w_hm = (const float*)d_in[5];  const float* b_hm = (const float*)d_in[6];
  const float* w_ce = (const float*)d_in[7];  const float* b_ce = (const float*)d_in[8];
  const float* w_cz = (const float*)d_in[9];  const float* b_cz = (const float*)d_in[10];
  const float* w_dm = (const float*)d_in[11]; const float* b_dm = (const float*)d_in[12];
  const float* w_rt = (const float*)d_in[13]; const float* b_rt = (const float*)d_in[14];
  float* out = (float*)d_out;

  char* ws = (char*)d_ws;
  unsigned short* w1t = (unsigned short*)ws;                   // 11,796,480 B
  unsigned short* fb  = (unsigned short*)(ws + 11796480);      // 10,240,000 B
  unsigned short* yb  = (unsigned short*)(ws + 22036480);      // 51,200,000 B
  float* sums = (float*)(ws + 73236480);                       // 5,120 B

  prep<<<5361, 256, 0, stream>>>((const float4*)feats, (ushort4*)fb, W1, w1t, sums);
  conv_gemm<<<1600, 512, 0, stream>>>(fb, nbr, w1t, yb, sums);
  head_fuse<<<3125, 256, 0, stream>>>(yb, sums, gamma, beta, w_hm, b_hm, w_ce, b_ce,
                                      w_cz, b_cz, w_dm, b_dm, w_rt, b_rt, out);
}

// Round 11
// 259.336 us; speedup vs baseline: 1.0441x; 1.0441x over previous
//
#include <hip/hip_runtime.h>
#include <stdint.h>

#define NVOX 40000
#define CCH  128
#define K2   9
#define NH   5
#define TILES 313   // ceil(40000/128)

typedef __attribute__((ext_vector_type(8))) short bf16x8;
typedef __attribute__((ext_vector_type(16))) float f32x16;

__device__ __forceinline__ unsigned short f2b(float f) {
  union { float f; unsigned int u; } v; v.f = f;
  return (unsigned short)((v.u + 0x7fffu + ((v.u >> 16) & 1u)) >> 16);
}
__device__ __forceinline__ float b2f(unsigned short u) {
  union { unsigned int u; float f; } v; v.u = ((unsigned int)u) << 16;
  return v.f;
}
__device__ __forceinline__ void g2l16(const void* g, void* l) {
  __builtin_amdgcn_global_load_lds(
      (const __attribute__((address_space(1))) unsigned int*)g,
      (__attribute__((address_space(3))) unsigned int*)l, 16, 0, 0);
}
// XOR-swizzled LDS address (shorts) for logical (row, short-col), 128-wide
__device__ __forceinline__ int swz(int row, int col) {
  return row * 128 + ((((col >> 3) ^ (row & 15)) << 3) | (col & 7));
}

// ---- fused prep: feats fp32->bf16 | W1 cvt+transpose | sums zero ----
__global__ void prep(const float4* __restrict__ feats, ushort4* __restrict__ fb,
                     const float* __restrict__ w1, unsigned short* __restrict__ w1t,
                     float* __restrict__ sums) {
  __shared__ unsigned short t[64 * 34];
  int b = blockIdx.x;
  if (b < 5000) {
    int i = b * 256 + threadIdx.x;
    if (i < NVOX * CCH / 4) {
      float4 v = feats[i];
      ushort4 r;
      r.x = f2b(v.x); r.y = f2b(v.y); r.z = f2b(v.z); r.w = f2b(v.w);
      fb[i] = r;
    }
    return;
  }
  if (b == 5360) {  // zero BN partial sums (ws is poisoned each call)
    for (int i = threadIdx.x; i < 2 * NH * CCH; i += 256) sums[i] = 0.f;
    return;
  }
  int bb = b - 5000;           // 0..359
  int tile = bb >> 3;          // h*9+k, 0..44
  int q = (bb >> 1) & 3;       // c-quarter (32 c each)
  int dh = bb & 1;             // d-half (64 d each)
  const float* src = w1 + (size_t)tile * 16384 + q * 32 * 128 + dh * 64;
  for (int e = threadIdx.x; e < 2048; e += 256) {
    int c = e >> 6, dd = e & 63;
    t[dd * 34 + c] = f2b(src[c * 128 + dd]);
  }
  __syncthreads();
  unsigned short* dst = w1t + (size_t)tile * 16384 + q * 32;
  for (int e = threadIdx.x; e < 2048; e += 256) {
    int d = e >> 5, c = e & 31;
    dst[(dh * 64 + d) * 128 + c] = t[d * 34 + c];
  }
}

// stage one full 128x128 bf16 B tile into LDS (swizzled), 8 g2l16 per wave x 4 waves
__device__ __forceinline__ void stageB(unsigned short* dstbuf, const unsigned short* wp,
                                       int wave, int lane) {
  int lcol = lane & 15, lrow = lane >> 4;
#pragma unroll
  for (int i = 0; i < 8; ++i) {
    int elem = wave * 4096 + i * 512;
    int row = (elem >> 7) + lrow;
    g2l16(wp + row * 128 + ((lcol ^ (row & 15)) << 3), &dstbuf[elem]);
  }
}

// ---- gather-GEMM v11: mfma_32x32x16, wave owns 64 rows x 64 cols ->
// FLOP per LDS-byte doubled vs R6 (MFMA-bound, not LDS-bound). A frags
// stream through a 4-slot register ring, prefetched 3 ksteps ahead; B
// full-tile double-buffered, staged at tap start, consumed next tap;
// tap-end = s_waitcnt vmcnt(6) (keeps the 6 newest A prefetches in
// flight, drains the B stage) + raw s_barrier. ----
__global__ void __launch_bounds__(256, 2) conv_gemm(
    const unsigned short* __restrict__ fb,   // feats bf16 [N][128]
    const int* __restrict__ nbr,             // [N][9]
    const unsigned short* __restrict__ w1t,  // [H][9][d=128][c=128] bf16
    unsigned short* __restrict__ yb,         // [H][N][128] bf16
    float* __restrict__ sums)                // [2][H][128]
{
  __shared__ __align__(16) unsigned short Bsb[2][128 * 128];  // 64 KB
  __shared__ int idxs[128 * K2];                              // 4.6 KB

  const int bid = blockIdx.x;
  const int s = bid / 40;
  const int r = bid % 40;
  const int h = r >> 3;        // 0..4
  const int x = r & 7;         // xcd lane
  const int tile = s * 8 + x;
  if (tile >= TILES) return;
  const int n0 = tile * 128;

  const int tid = threadIdx.x;
  const int wave = tid >> 6;   // 0..3
  const int lane = tid & 63;
  const int l31 = lane & 31;
  const int hi  = lane >> 5;   // 0,1 -> k-half of the 32x32 fragment
  const int rg = wave >> 1;    // row group: rows rg*64 .. +64
  const int cg = wave & 1;     // col group: cols cg*64 .. +64

  const unsigned short* wh = w1t + ((size_t)h * K2 << 14);

  // B(0) stage first (no idx dependency)
  stageB(Bsb[0], wh, wave, lane);

  for (int i = tid; i < 128 * K2; i += 256) {
    int rr = i / K2;
    int gn = n0 + rr; if (gn > NVOX - 1) gn = NVOX - 1;
    idxs[i] = nbr[gn * K2 + (i - rr * K2)];
  }
  __syncthreads();   // idxs visible (also drains B(0))

  // A register ring: slot g&3 holds global kstep g (tap g>>3, kstep g&7);
  // frag layout: A[m=lane&31][k=hi*8+j], rows rg*64 + rt*32 + l31.
  bf16x8 Ar[4][2];
#define LOAD_A(SLOT, G)                                                        \
  {                                                                            \
    int tp = (G) >> 3, ksx = (G) & 7;                                          \
    int i0 = idxs[(rg * 64 + l31) * K2 + tp];                                  \
    int i1 = idxs[(rg * 64 + 32 + l31) * K2 + tp];                             \
    Ar[SLOT][0] = *(const bf16x8*)(fb + (size_t)i0 * CCH + ksx * 16 + hi * 8); \
    Ar[SLOT][1] = *(const bf16x8*)(fb + (size_t)i1 * CCH + ksx * 16 + hi * 8); \
  }

  LOAD_A(0, 0)
  LOAD_A(1, 1)
  LOAD_A(2, 2)
  asm volatile("s_waitcnt vmcnt(0)" ::: "memory");
  __syncthreads();   // B(0) + A(0..2) ready

  f32x16 acc[2][2] = {};

#pragma unroll
  for (int k = 0; k < K2; ++k) {
    if (k + 1 < K2)
      stageB(Bsb[(k + 1) & 1], wh + ((size_t)(k + 1) << 14), wave, lane);
    const unsigned short* Bcur = Bsb[k & 1];

#pragma unroll
    for (int ks = 0; ks < 8; ++ks) {
      const int g = k * 8 + ks;
      if (g + 3 < 72) LOAD_A((g + 3) & 3, g + 3)
      // B frags: LDS row = out-col, chunk = ks*2 + hi, un-swizzle by row&15
      const int slotc = ((ks * 2 + hi) ^ (l31 & 15)) << 3;
      bf16x8 b0 = *(const bf16x8*)&Bcur[(cg * 64 + l31) * 128 + slotc];
      bf16x8 b1 = *(const bf16x8*)&Bcur[(cg * 64 + 32 + l31) * 128 + slotc];
      acc[0][0] = __builtin_amdgcn_mfma_f32_32x32x16_bf16(Ar[g & 3][0], b0, acc[0][0], 0, 0, 0);
      acc[0][1] = __builtin_amdgcn_mfma_f32_32x32x16_bf16(Ar[g & 3][0], b1, acc[0][1], 0, 0, 0);
      acc[1][0] = __builtin_amdgcn_mfma_f32_32x32x16_bf16(Ar[g & 3][1], b0, acc[1][0], 0, 0, 0);
      acc[1][1] = __builtin_amdgcn_mfma_f32_32x32x16_bf16(Ar[g & 3][1], b1, acc[1][1], 0, 0, 0);
    }

    if (k + 1 < K2) {
      // drain everything except the 6 newest loads (3 ksteps x 2 A prefetches)
      asm volatile("s_waitcnt vmcnt(6)" ::: "memory");
      __builtin_amdgcn_s_barrier();
    }
  }
#undef LOAD_A
  __syncthreads();   // all waves done reading Bsb[0] (tap 8)

  // ---- epilogue ----
  const bool full = (n0 + 128 <= NVOX);
  unsigned short* epi = &Bsb[0][0];   // 32 KB swizzled y-transpose
  // 32x32 C/D layout: col = lane&31, row = (reg&3) + 8*(reg>>2) + 4*hi
#pragma unroll
  for (int rt = 0; rt < 2; ++rt)
#pragma unroll
    for (int ct = 0; ct < 2; ++ct)
#pragma unroll
      for (int reg = 0; reg < 16; ++reg) {
        int rloc = rg * 64 + rt * 32 + (reg & 3) + 8 * (reg >> 2) + 4 * hi;
        int col = cg * 64 + ct * 32 + l31;
        epi[swz(rloc, col)] = f2b(acc[rt][ct][reg]);
      }

  // BN partials from acc (per-lane column = cg*64 + ct*32 + l31)
  float psm[2] = {0.f, 0.f}, pq[2] = {0.f, 0.f};
#pragma unroll
  for (int ct = 0; ct < 2; ++ct) {
#pragma unroll
    for (int rt = 0; rt < 2; ++rt)
#pragma unroll
      for (int reg = 0; reg < 16; ++reg) {
        float v = acc[rt][ct][reg];
        if (!full) {
          int rloc = rg * 64 + rt * 32 + (reg & 3) + 8 * (reg >> 2) + 4 * hi;
          if (n0 + rloc >= NVOX) v = 0.f;
        }
        psm[ct] += v; pq[ct] += v * v;
      }
    psm[ct] += __shfl_xor(psm[ct], 32);   // merge k-halves (same column)
    pq[ct]  += __shfl_xor(pq[ct], 32);
  }
  __syncthreads();   // epi written; Bsb[1] free for pb

  float2* pb = (float2*)&Bsb[1][0];   // [128 cols][2 rg] float2 = 2 KB
  if (hi == 0)
#pragma unroll
    for (int ct = 0; ct < 2; ++ct)
      pb[(cg * 64 + ct * 32 + l31) * 2 + rg] = make_float2(psm[ct], pq[ct]);

  // coalesced y store (un-swizzle on read)
  for (int i = tid; i < 2048; i += 256) {
    int row = i >> 4;
    int c = i & 15;
    if (n0 + row < NVOX)
      *(bf16x8*)(yb + ((size_t)h * NVOX + n0 + row) * CCH + c * 8) =
          *(const bf16x8*)&epi[row * 128 + ((c ^ (row & 15)) << 3)];
  }
  __syncthreads();

  if (tid < 128) {
    float2 p0 = pb[tid * 2 + 0], p1 = pb[tid * 2 + 1];
    atomicAdd(&sums[h * CCH + tid], p0.x + p1.x);
    atomicAdd(&sums[NH * CCH + h * CCH + tid], p0.y + p1.y);
  }
}

// ---- BN + ReLU + 1x1 head, one (64-voxel tile, head) per block ----
__global__ void __launch_bounds__(256) head_fuse(
    const unsigned short* __restrict__ yb, const float* __restrict__ sums,
    const float* __restrict__ gamma, const float* __restrict__ beta,
    const float* __restrict__ w_hm, const float* __restrict__ b_hm,
    const float* __restrict__ w_ce, const float* __restrict__ b_ce,
    const float* __restrict__ w_cz, const float* __restrict__ b_cz,
    const float* __restrict__ w_dm, const float* __restrict__ b_dm,
    const float* __restrict__ w_rt, const float* __restrict__ b_rt,
    float* __restrict__ out)
{
  __shared__ unsigned short t[64 * 128];   // 16 KB, swizzled
  __shared__ float pbuf[4][64][3];         // 3 KB
  __shared__ float scl[CCH], shf[CCH];     // 1 KB

  const int tid = threadIdx.x;
  const int h  = blockIdx.x % NH;
  const int v0 = (blockIdx.x / NH) * 64;   // 625 v-tiles cover 40000
  const int vx = tid & 63;
  const int qd = tid >> 6;                 // wave-uniform d-quarter

  const float* wp; const float* bp; int oc, off;
  switch (h) {
    case 0: wp = w_hm; bp = b_hm; oc = 3; off = 0; break;
    case 1: wp = w_ce; bp = b_ce; oc = 2; off = 3; break;
    case 2: wp = w_cz; bp = b_cz; oc = 1; off = 5; break;
    case 3: wp = w_dm; bp = b_dm; oc = 3; off = 6; break;
    default: wp = w_rt; bp = b_rt; oc = 2; off = 9; break;
  }

  if (tid < CCH) {
    int i = h * CCH + tid;
    float mean = sums[i] * (1.f / NVOX);
    float var = sums[NH * CCH + i] * (1.f / NVOX) - mean * mean;
    float rstd = rsqrtf(var + 1e-5f);
    float sc = rstd * gamma[i];
    scl[tid] = sc;
    shf[tid] = beta[i] - mean * sc;
  }
#pragma unroll
  for (int i = 0; i < 4; ++i) {
    int idx = i * 256 + tid;
    int row = idx >> 4, c = idx & 15;
    *(bf16x8*)&t[row * 128 + ((c ^ (row & 15)) << 3)] =
        *(const bf16x8*)(yb + ((size_t)h * NVOX + v0 + row) * CCH + c * 8);
  }
  __syncthreads();

  float p0 = 0.f, p1 = 0.f, p2 = 0.f;
#pragma unroll
  for (int qq = 0; qq < 4; ++qq) {
    int q8 = qd * 4 + qq;
    bf16x8 pk = *(const bf16x8*)&t[vx * 128 + ((q8 ^ (vx & 15)) << 3)];
#pragma unroll
    for (int e = 0; e < 8; ++e) {
      int d = q8 * 8 + e;
      float z = fmaf(b2f((unsigned short)pk[e]), scl[d], shf[d]);
      z = fmaxf(z, 0.f);
      const float* wr = wp + d * oc;
      p0 = fmaf(z, wr[0], p0);
      if (oc > 1) p1 = fmaf(z, wr[1], p1);
      if (oc > 2) p2 = fmaf(z, wr[2], p2);
    }
  }
  pbuf[qd][vx][0] = p0;
  if (oc > 1) pbuf[qd][vx][1] = p1;
  if (oc > 2) pbuf[qd][vx][2] = p2;
  __syncthreads();

  if (tid < 64) {
    float* op = out + (size_t)(v0 + tid) * 11 + off;
#pragma unroll
    for (int j = 0; j < 3; ++j)
      if (j < oc)
        op[j] = bp[j] + pbuf[0][tid][j] + pbuf[1][tid][j] + pbuf[2][tid][j] + pbuf[3][tid][j];
  }
}

extern "C" void kernel_launch(void* const* d_in, const int* in_sizes, int n_in,
                              void* d_out, int out_size, void* d_ws, size_t ws_size,
                              hipStream_t stream) {
  const float* feats = (const float*)d_in[0];
  const int*   nbr   = (const int*)d_in[1];
  const float* W1    = (const float*)d_in[2];
  const float* gamma = (const float*)d_in[3];
  const float* beta  = (const float*)d_in[4];
  const float* w_hm = (const float*)d_in[5];  const float* b_hm = (const float*)d_in[6];
  const float* w_ce = (const float*)d_in[7];  const float* b_ce = (const float*)d_in[8];
  const float* w_cz = (const float*)d_in[9];  const float* b_cz = (const float*)d_in[10];
  const float* w_dm = (const float*)d_in[11]; const float* b_dm = (const float*)d_in[12];
  const float* w_rt = (const float*)d_in[13]; const float* b_rt = (const float*)d_in[14];
  float* out = (float*)d_out;

  char* ws = (char*)d_ws;
  unsigned short* w1t = (unsigned short*)ws;                   // 11,796,480 B
  unsigned short* fb  = (unsigned short*)(ws + 11796480);      // 10,240,000 B
  unsigned short* yb  = (unsigned short*)(ws + 22036480);      // 51,200,000 B
  float* sums = (float*)(ws + 73236480);                       // 5,120 B

  prep<<<5361, 256, 0, stream>>>((const float4*)feats, (ushort4*)fb, W1, w1t, sums);
  conv_gemm<<<1600, 256, 0, stream>>>(fb, nbr, w1t, yb, sums);
  head_fuse<<<3125, 256, 0, stream>>>(yb, sums, gamma, beta, w_hm, b_hm, w_ce, b_ce,
                                      w_cz, b_cz, w_dm, b_dm, w_rt, b_rt, out);
}